// Round 10
// baseline (32.116 us; speedup 1.0000x reference)
//
#include <hip/hip_runtime.h>

// Problem constants: x[64][32768][15] f32, hidden sizes 4/4/4.
#define SEQ   64
#define BATCH 32768
#define FEAT  15
#define SLABBYTES (BATCH * FEAT * 4)   // 1,966,080 bytes per timestep slab

#define LOG2E 1.4426950408889634f

typedef float v2f __attribute__((ext_vector_type(2)));
typedef float v4f __attribute__((ext_vector_type(4)));

__device__ __forceinline__ float fast_rcp(float x) { return __builtin_amdgcn_rcpf(x); }
__device__ __forceinline__ float ex2(float x)      { return __builtin_amdgcn_exp2f(x); }
// sig2(t) = 1/(1+2^t).  sigmoid(x) = sig2(-L*x); tanh(x) = 1 - 2*sig2(2L*x).
__device__ __forceinline__ float sig2(float t)     { return fast_rcp(1.0f + ex2(t)); }

// Quad (4-lane) DPP move: CTRL = j*0x55 broadcasts lane j of each quad.
template <int CTRL>
__device__ __forceinline__ float qmov(float v) {
    return __int_as_float(
        __builtin_amdgcn_mov_dpp(__float_as_int(v), CTRL, 0xf, 0xf, false));
}

// packed f32 fma -> v_pk_fma_f32
__device__ __forceinline__ v2f fma2(v2f a, v2f b, v2f c) { return a * b + c; }

template <int N>
__device__ __forceinline__ void waitv() {
    asm volatile("s_waitcnt vmcnt(%0)" :: "n"(N) : "memory");
}
template <int N>
__device__ __forceinline__ void waitlg() {
    asm volatile("s_waitcnt lgkmcnt(%0)" :: "n"(N) : "memory");
}

typedef const __attribute__((address_space(1))) void gas_t;
typedef __attribute__((address_space(3))) void las_t;

__global__ __launch_bounds__(256, 2) void lstm_fused(
    const float* __restrict__ x,
    const float* __restrict__ w1,  const float* __restrict__ b1,
    const float* __restrict__ w2,  const float* __restrict__ b2,
    const float* __restrict__ wih, const float* __restrict__ whh,
    const float* __restrict__ bih, const float* __restrict__ bhh,
    const float* __restrict__ w3,  const float* __restrict__ b3,
    float* __restrict__ out)
{
    // 4 waves/block; per wave: 16-buffer DMA ring, 1 KiB per buffer
    // (16 rows x 64 B). 64 KiB/block total; 2 blocks/CU -> 128 of 160 KiB.
    // Ring depth 16 (vs 8 in R8) puts ~30 KB/CU in flight: comfortably above
    // the ~15 KB Little's-law requirement at loaded latency, so the memory
    // queue never starves.
    __shared__ __align__(16) float lds[4][16][256];

    const int tid = threadIdx.x;
    const int w   = tid >> 6;          // wave in block
    const int l   = tid & 63;          // lane
    const int u   = l & 3;             // lane-in-quad (owns hidden unit u)
    const int e   = l >> 2;            // element (=row) within the wave's 16
    const int ebase = blockIdx.x * 64 + w * 16;
    const int elem  = ebase + e;

    // ---- DMA source pre-swizzle (dest is linear: lane k -> bytes [16k,16k+16)) ----
    // dest lane k covers row r=k>>2, slot q=k&3. Layout: slot q of row r holds
    // part p = (q - perm(r)) & 3, perm(r) = (r + (r>>2)) & 3  (2-way banks max).
    // Parts: p0=bytes 0..15, p1=16..31, p2=32..47, p3=44..59 (word 11 dup; never
    // crosses the slab end, so no OOB).
    const int perm_e = (e + (e >> 2)) & 3;
    const int p      = (u - perm_e) & 3;
    const int inrow  = (p < 3) ? p * 16 : 44;
    uint32_t off = (uint32_t)(ebase + e) * 60u + (uint32_t)inrow;   // slab-0 source byte

    auto gload = [&](int b, uint32_t o) {
        __builtin_amdgcn_global_load_lds(
            (gas_t*)((const char*)x + o),
            (las_t*)&lds[w][b][0], 16, 0, 0);
    };

    // ---- reader-side slot bases (float index within a buffer) for parts 0..3 ----
    int sb[4];
#pragma unroll
    for (int pp = 0; pp < 4; ++pp) sb[pp] = (4 * e + ((pp + perm_e) & 3)) * 4;

    auto ldrow = [&](int b, v4f& F0, v4f& F1, v4f& F2, v4f& F3) {
        const float* B = &lds[w][b][0];
        F0 = *(const v4f*)(B + sb[0]);   // words 0..3
        F1 = *(const v4f*)(B + sb[1]);   // words 4..7
        F2 = *(const v4f*)(B + sb[2]);   // words 8..11
        F3 = *(const v4f*)(B + sb[3]);   // words 11..14 (x = dup of 11)
    };

    // ---- weights ----
    // fc1 (unit u) packed as v2f pairs over feature pairs
    // (0,1)(4,5)(8,9)(11dup->0,12) chain A; (2,3)(6,7)(10,11)(13,14) chain B.
    v2f PA0, PA1, PA2, PA3, PB0, PB1, PB2, PB3, SEEDv;
    {
        const float* r = w1 + u * FEAT;
        PA0 = v2f{r[0],  r[1]};  PB0 = v2f{r[2],  r[3]};
        PA1 = v2f{r[4],  r[5]};  PB1 = v2f{r[6],  r[7]};
        PA2 = v2f{r[8],  r[9]};  PB2 = v2f{r[10], r[11]};
        PA3 = v2f{0.0f,  r[12]}; PB3 = v2f{r[13], r[14]};
        SEEDv = v2f{b1[u], 0.0f};
    }
    float W2s[4];
#pragma unroll
    for (int j = 0; j < 4; ++j) W2s[j] = -LOG2E * w2[u * 4 + j];
    const float B2v = -LOG2E * b2[u];
    v2f WIp[4][2], WHp[4][2], BIg[4];
#pragma unroll
    for (int g = 0; g < 4; ++g) {
        const float sg = (g == 2) ? (2.0f * LOG2E) : -LOG2E;   // torch order i,f,g,o
        const int row = (g * 4 + u) * 4;
        WIp[g][0] = v2f{sg * wih[row + 0], sg * wih[row + 1]};
        WIp[g][1] = v2f{sg * wih[row + 2], sg * wih[row + 3]};
        WHp[g][0] = v2f{sg * whh[row + 0], sg * whh[row + 1]};
        WHp[g][1] = v2f{sg * whh[row + 2], sg * whh[row + 3]};
        BIg[g]    = v2f{sg * (bih[g * 4 + u] + bhh[g * 4 + u]), 0.0f};
    }
    const float W3v = -LOG2E * w3[u];
    const float B3v = -LOG2E * b3[0];

    float h = 0.0f, c = 0.0f;

    auto step = [&](v4f F0, v4f F1, v4f F2, v4f F3) {
        // fc1 (unit u): 8 pk_fma over aligned v2f slices (word-11 dup zeroed)
        v2f accA = fma2(PA0, F0.xy, fma2(PA1, F1.xy,
                   fma2(PA2, F2.xy, fma2(PA3, F3.xy, SEEDv))));
        v2f accB = fma2(PB0, F0.zw, fma2(PB1, F1.zw,
                   fma2(PB2, F2.zw, fma2(PB3, F3.zw, v2f{0.0f, 0.0f}))));
        const v2f accS = accA + accB;
        const float h1 = fmaxf(accS.x + accS.y, 0.0f);
        // fc2 (unit u) + sigmoid
        const float t0 = qmov<0x00>(h1), t1 = qmov<0x55>(h1);
        const float t2 = qmov<0xAA>(h1), t3 = qmov<0xFF>(h1);
        const float a2n = fmaf(W2s[0], t0, fmaf(W2s[1], t1,
                          fmaf(W2s[2], t2, fmaf(W2s[3], t3, B2v))));
        const float h2 = sig2(a2n);
        // gates (packed over j)
        const v2f q01 = v2f{qmov<0x00>(h2), qmov<0x55>(h2)};
        const v2f q23 = v2f{qmov<0xAA>(h2), qmov<0xFF>(h2)};
        v2f A[4];
#pragma unroll
        for (int g = 0; g < 4; ++g)
            A[g] = fma2(WIp[g][0], q01, fma2(WIp[g][1], q23, BIg[g]));
        const v2f h01 = v2f{qmov<0x00>(h), qmov<0x55>(h)};
        const v2f h23 = v2f{qmov<0xAA>(h), qmov<0xFF>(h)};
#pragma unroll
        for (int g = 0; g < 4; ++g)
            A[g] = fma2(WHp[g][0], h01, fma2(WHp[g][1], h23, A[g]));
        const float ig = sig2(A[0].x + A[0].y);
        const float fg = sig2(A[1].x + A[1].y);
        const float gt = fmaf(-2.0f, sig2(A[2].x + A[2].y), 1.0f);
        const float og = sig2(A[3].x + A[3].y);
        c = fmaf(fg, c, ig * gt);
        const float tc = fmaf(-2.0f, sig2(c * (2.0f * LOG2E)), 1.0f);
        h = og * tc;
    };

    // ---- prologue: fill the 16-deep ring (slabs 0..15), read row 0 ----
#pragma unroll
    for (int b = 0; b < 16; ++b) { gload(b, off); off += SLABBYTES; }
    waitv<15>();                                 // slab 0 landed
    __builtin_amdgcn_sched_barrier(0);
    v4f F0, F1, F2, F3;
    ldrow(0, F0, F1, F2, F3);

    // ---- main loop: steps 0..47; steady state = 15-16 DMAs in flight ----
    // At step s: outstanding = slabs s+1..s+15; drain to 14 retires slab s+1.
#pragma unroll 1
    for (int ph = 0; ph < 3; ++ph) {
#pragma unroll
        for (int j = 0; j < 16; ++j) {           // step s = 16*ph + j
            waitv<14>();                         // slab s+1 landed
            __builtin_amdgcn_sched_barrier(0);
            v4f G0, G1, G2, G3;
            ldrow((j + 1) & 15, G0, G1, G2, G3); // row s+1
            waitlg<4>();                         // row-s reads retired -> buf s&15 free
            __builtin_amdgcn_sched_barrier(0);
            gload(j, off);  off += SLABBYTES;    // slab s+16 -> buffer s&15
            step(F0, F1, F2, F3);                // compute step s
            F0 = G0; F1 = G1; F2 = G2; F3 = G3;
        }
    }
    // ---- epilogue: steps 48..63, ring drains; at step s outstanding = 63-s ----
#define EPI(JJ, NN)                                                   \
    {   waitv<NN>();                                                  \
        __builtin_amdgcn_sched_barrier(0);                            \
        v4f G0, G1, G2, G3;                                           \
        ldrow(((JJ) + 1) & 15, G0, G1, G2, G3);                       \
        step(F0, F1, F2, F3);                                         \
        F0 = G0; F1 = G1; F2 = G2; F3 = G3; }
    EPI(0, 14)  EPI(1, 13)  EPI(2, 12)  EPI(3, 11)
    EPI(4, 10)  EPI(5, 9)   EPI(6, 8)   EPI(7, 7)
    EPI(8, 6)   EPI(9, 5)   EPI(10, 4)  EPI(11, 3)
    EPI(12, 2)  EPI(13, 1)  EPI(14, 0)
#undef EPI
    step(F0, F1, F2, F3);                        // step 63

    // ---- head: out[e] = sigmoid(w3·h + b3), quad reduction (scaled) ----
    float pr = W3v * h;
    pr += qmov<0xB1>(pr);
    pr += qmov<0x4E>(pr);
    if (u == 0) out[elem] = sig2(pr + B3v);
}

extern "C" void kernel_launch(void* const* d_in, const int* in_sizes, int n_in,
                              void* d_out, int out_size, void* d_ws, size_t ws_size,
                              hipStream_t stream) {
    (void)in_sizes; (void)n_in; (void)d_ws; (void)ws_size; (void)out_size;
    const float* x   = (const float*)d_in[0];
    const float* w1  = (const float*)d_in[1];
    const float* b1  = (const float*)d_in[2];
    const float* w2  = (const float*)d_in[3];
    const float* b2  = (const float*)d_in[4];
    const float* wih = (const float*)d_in[5];
    const float* whh = (const float*)d_in[6];
    const float* bih = (const float*)d_in[7];
    const float* bhh = (const float*)d_in[8];
    const float* w3  = (const float*)d_in[9];
    const float* b3  = (const float*)d_in[10];
    float* out = (float*)d_out;

    // 512 blocks x 256 threads = 2048 waves; one quad (4 lanes) per batch element.
    lstm_fused<<<dim3(512), dim3(256), 0, stream>>>(
        x, w1, b1, w2, b2, wih, whh, bih, bhh, w3, b3, out);
}

// Round 11
// 29.754 us; speedup vs baseline: 1.0794x; 1.0794x over previous
//
#include <hip/hip_runtime.h>

// Problem constants: x[64][32768][15] f32, hidden sizes 4/4/4.
#define SEQ   64
#define BATCH 32768
#define FEAT  15
#define SLABBYTES (BATCH * FEAT * 4)   // 1,966,080 bytes per timestep slab

#define LOG2E 1.4426950408889634f

typedef float v2f __attribute__((ext_vector_type(2)));
typedef float v4f __attribute__((ext_vector_type(4)));

__device__ __forceinline__ float fast_rcp(float x) { return __builtin_amdgcn_rcpf(x); }
__device__ __forceinline__ float ex2(float x)      { return __builtin_amdgcn_exp2f(x); }
// sig2(t) = 1/(1+2^t).  sigmoid(x) = sig2(-L*x); tanh(x) = 1 - 2*sig2(2L*x).
__device__ __forceinline__ float sig2(float t)     { return fast_rcp(1.0f + ex2(t)); }

// Quad (4-lane) DPP move: CTRL = j*0x55 broadcasts lane j of each quad.
template <int CTRL>
__device__ __forceinline__ float qmov(float v) {
    return __int_as_float(
        __builtin_amdgcn_mov_dpp(__float_as_int(v), CTRL, 0xf, 0xf, false));
}

// packed f32 fma -> v_pk_fma_f32
__device__ __forceinline__ v2f fma2(v2f a, v2f b, v2f c) { return a * b + c; }

template <int N>
__device__ __forceinline__ void waitv() {
    asm volatile("s_waitcnt vmcnt(%0)" :: "n"(N) : "memory");
}

typedef const __attribute__((address_space(1))) void gas_t;
typedef __attribute__((address_space(3))) void las_t;

__global__ __launch_bounds__(256, 2) void lstm_fused(
    const float* __restrict__ x,
    const float* __restrict__ w1,  const float* __restrict__ b1,
    const float* __restrict__ w2,  const float* __restrict__ b2,
    const float* __restrict__ wih, const float* __restrict__ whh,
    const float* __restrict__ bih, const float* __restrict__ bhh,
    const float* __restrict__ w3,  const float* __restrict__ b3,
    float* __restrict__ out)
{
    // 4 waves/block; per wave: 8 LDS buffers (1 KiB each), but only SIX DMAs
    // outstanding (depth-6 ring): R10 showed depth 16 < depth 8; probing the
    // congestion curve downward. 32 KiB/block.
    __shared__ __align__(16) float lds[4][8][256];

    const int tid = threadIdx.x;
    const int w   = tid >> 6;          // wave in block
    const int l   = tid & 63;          // lane
    const int u   = l & 3;             // lane-in-quad (owns hidden unit u)
    const int e   = l >> 2;            // element (=row) within the wave's 16
    const int ebase = blockIdx.x * 64 + w * 16;
    const int elem  = ebase + e;

    // ---- DMA source pre-swizzle (dest is linear: lane k -> bytes [16k,16k+16)) ----
    // dest lane k covers row r=k>>2, slot q=k&3. Layout: slot q of row r holds
    // part p = (q - perm(r)) & 3, perm(r) = (r + (r>>2)) & 3  (2-way banks max).
    // Parts: p0=bytes 0..15, p1=16..31, p2=32..47, p3=44..59 (word 11 dup; never
    // crosses the slab end, so no OOB).
    const int perm_e = (e + (e >> 2)) & 3;
    const int p      = (u - perm_e) & 3;
    const int inrow  = (p < 3) ? p * 16 : 44;
    uint32_t off = (uint32_t)(ebase + e) * 60u + (uint32_t)inrow;   // slab-0 source byte

    auto gload = [&](int b, uint32_t o) {
        __builtin_amdgcn_global_load_lds(
            (gas_t*)((const char*)x + o),
            (las_t*)&lds[w][b][0], 16, 0, 0);
    };

    // ---- reader-side slot bases (float index within a buffer) for parts 0..3 ----
    int sb[4];
#pragma unroll
    for (int pp = 0; pp < 4; ++pp) sb[pp] = (4 * e + ((pp + perm_e) & 3)) * 4;

    auto ldrow = [&](int b, v4f& F0, v4f& F1, v4f& F2, v4f& F3) {
        const float* B = &lds[w][b][0];
        F0 = *(const v4f*)(B + sb[0]);   // words 0..3
        F1 = *(const v4f*)(B + sb[1]);   // words 4..7
        F2 = *(const v4f*)(B + sb[2]);   // words 8..11
        F3 = *(const v4f*)(B + sb[3]);   // words 11..14 (x = dup of 11)
    };

    // ---- weights ----
    // fc1 (unit u) packed as v2f pairs: chains A=(0,1)(4,5)(8,9)(0*,12),
    // B=(2,3)(6,7)(10,11)(13,14); word-11 dup in F3.x gets a zero weight.
    v2f PA0, PA1, PA2, PA3, PB0, PB1, PB2, PB3, SEEDv;
    {
        const float* r = w1 + u * FEAT;
        PA0 = v2f{r[0],  r[1]};  PB0 = v2f{r[2],  r[3]};
        PA1 = v2f{r[4],  r[5]};  PB1 = v2f{r[6],  r[7]};
        PA2 = v2f{r[8],  r[9]};  PB2 = v2f{r[10], r[11]};
        PA3 = v2f{0.0f,  r[12]}; PB3 = v2f{r[13], r[14]};
        SEEDv = v2f{b1[u], 0.0f};
    }
    float W2s[4];
#pragma unroll
    for (int j = 0; j < 4; ++j) W2s[j] = -LOG2E * w2[u * 4 + j];
    const float B2v = -LOG2E * b2[u];
    v2f WIp[4][2], WHp[4][2], BIg[4];
#pragma unroll
    for (int g = 0; g < 4; ++g) {
        const float sg = (g == 2) ? (2.0f * LOG2E) : -LOG2E;   // torch order i,f,g,o
        const int row = (g * 4 + u) * 4;
        WIp[g][0] = v2f{sg * wih[row + 0], sg * wih[row + 1]};
        WIp[g][1] = v2f{sg * wih[row + 2], sg * wih[row + 3]};
        WHp[g][0] = v2f{sg * whh[row + 0], sg * whh[row + 1]};
        WHp[g][1] = v2f{sg * whh[row + 2], sg * whh[row + 3]};
        BIg[g]    = v2f{sg * (bih[g * 4 + u] + bhh[g * 4 + u]), 0.0f};
    }
    const float W3v = -LOG2E * w3[u];
    const float B3v = -LOG2E * b3[0];

    float h = 0.0f, c = 0.0f;

    auto step = [&](v4f F0, v4f F1, v4f F2, v4f F3) {
        // fc1 (unit u): 8 pk_fma over aligned v2f slices
        v2f accA = fma2(PA0, F0.xy, fma2(PA1, F1.xy,
                   fma2(PA2, F2.xy, fma2(PA3, F3.xy, SEEDv))));
        v2f accB = fma2(PB0, F0.zw, fma2(PB1, F1.zw,
                   fma2(PB2, F2.zw, fma2(PB3, F3.zw, v2f{0.0f, 0.0f}))));
        const v2f accS = accA + accB;
        const float h1 = fmaxf(accS.x + accS.y, 0.0f);
        // fc2 (unit u) + sigmoid
        const float t0 = qmov<0x00>(h1), t1 = qmov<0x55>(h1);
        const float t2 = qmov<0xAA>(h1), t3 = qmov<0xFF>(h1);
        const float a2n = fmaf(W2s[0], t0, fmaf(W2s[1], t1,
                          fmaf(W2s[2], t2, fmaf(W2s[3], t3, B2v))));
        const float h2 = sig2(a2n);
        // gates (packed over j)
        const v2f q01 = v2f{qmov<0x00>(h2), qmov<0x55>(h2)};
        const v2f q23 = v2f{qmov<0xAA>(h2), qmov<0xFF>(h2)};
        v2f A[4];
#pragma unroll
        for (int g = 0; g < 4; ++g)
            A[g] = fma2(WIp[g][0], q01, fma2(WIp[g][1], q23, BIg[g]));
        const v2f h01 = v2f{qmov<0x00>(h), qmov<0x55>(h)};
        const v2f h23 = v2f{qmov<0xAA>(h), qmov<0xFF>(h)};
#pragma unroll
        for (int g = 0; g < 4; ++g)
            A[g] = fma2(WHp[g][0], h01, fma2(WHp[g][1], h23, A[g]));
        const float ig = sig2(A[0].x + A[0].y);
        const float fg = sig2(A[1].x + A[1].y);
        const float gt = fmaf(-2.0f, sig2(A[2].x + A[2].y), 1.0f);
        const float og = sig2(A[3].x + A[3].y);
        c = fmaf(fg, c, ig * gt);
        const float tc = fmaf(-2.0f, sig2(c * (2.0f * LOG2E)), 1.0f);
        h = og * tc;
    };

    // ---- prologue: issue 6 DMAs (slabs 0..5), read row 0 ----
#pragma unroll
    for (int b = 0; b < 6; ++b) { gload(b, off); off += SLABBYTES; }
    waitv<5>();                                  // slab 0 landed
    __builtin_amdgcn_sched_barrier(0);
    v4f F0, F1, F2, F3;
    ldrow(0, F0, F1, F2, F3);

    // ---- main loop: steps 0..55; steady state = 5-6 DMAs in flight ----
    // At step s: issued slabs 0..s+5; need slab s+1 -> outstanding <= 4.
#pragma unroll 1
    for (int ph = 0; ph < 7; ++ph) {
#pragma unroll
        for (int j = 0; j < 8; ++j) {            // step s = 8*ph + j
            waitv<4>();                          // slab s+1 landed
            __builtin_amdgcn_sched_barrier(0);
            v4f G0, G1, G2, G3;
            ldrow((j + 1) & 7, G0, G1, G2, G3);  // row s+1
            gload((j + 6) & 7, off);             // slab s+6 -> buffer (s+6)&7
            off += SLABBYTES;
            __builtin_amdgcn_sched_barrier(0);
            step(F0, F1, F2, F3);                // compute step s
            F0 = G0; F1 = G1; F2 = G2; F3 = G3;
        }
    }
    // ---- epilogue: steps 56..62 drain (issued slabs 0..61), then step 63 ----
#define EPI(JJ, NN)                                                   \
    {   waitv<NN>();                                                  \
        __builtin_amdgcn_sched_barrier(0);                            \
        v4f G0, G1, G2, G3;                                           \
        ldrow(((JJ) + 1) & 7, G0, G1, G2, G3);                        \
        step(F0, F1, F2, F3);                                         \
        F0 = G0; F1 = G1; F2 = G2; F3 = G3; }
    EPI(0, 4) EPI(1, 3) EPI(2, 2) EPI(3, 1) EPI(4, 0) EPI(5, 0) EPI(6, 0)
#undef EPI
    step(F0, F1, F2, F3);                        // step 63

    // ---- head: out[e] = sigmoid(w3·h + b3), quad reduction (scaled) ----
    float pr = W3v * h;
    pr += qmov<0xB1>(pr);
    pr += qmov<0x4E>(pr);
    if (u == 0) out[elem] = sig2(pr + B3v);
}

extern "C" void kernel_launch(void* const* d_in, const int* in_sizes, int n_in,
                              void* d_out, int out_size, void* d_ws, size_t ws_size,
                              hipStream_t stream) {
    (void)in_sizes; (void)n_in; (void)d_ws; (void)ws_size; (void)out_size;
    const float* x   = (const float*)d_in[0];
    const float* w1  = (const float*)d_in[1];
    const float* b1  = (const float*)d_in[2];
    const float* w2  = (const float*)d_in[3];
    const float* b2  = (const float*)d_in[4];
    const float* wih = (const float*)d_in[5];
    const float* whh = (const float*)d_in[6];
    const float* bih = (const float*)d_in[7];
    const float* bhh = (const float*)d_in[8];
    const float* w3  = (const float*)d_in[9];
    const float* b3  = (const float*)d_in[10];
    float* out = (float*)d_out;

    // 512 blocks x 256 threads = 2048 waves; one quad (4 lanes) per batch element.
    lstm_fused<<<dim3(512), dim3(256), 0, stream>>>(
        x, w1, b1, w2, b2, wih, whh, bih, bhh, w3, b3, out);
}

// Round 12
// 29.085 us; speedup vs baseline: 1.1042x; 1.0230x over previous
//
#include <hip/hip_runtime.h>

// Problem constants: x[64][32768][15] f32, hidden sizes 4/4/4.
#define SEQ   64
#define BATCH 32768
#define FEAT  15
#define SLABBYTES (BATCH * FEAT * 4)   // 1,966,080 bytes per timestep slab

#define LOG2E 1.4426950408889634f

typedef float v2f __attribute__((ext_vector_type(2)));
typedef float v4f __attribute__((ext_vector_type(4)));

__device__ __forceinline__ float fast_rcp(float x) { return __builtin_amdgcn_rcpf(x); }
__device__ __forceinline__ float ex2(float x)      { return __builtin_amdgcn_exp2f(x); }
// sig2(t) = 1/(1+2^t).  sigmoid(x) = sig2(-L*x); tanh(x) = 1 - 2*sig2(2L*x).
__device__ __forceinline__ float sig2(float t)     { return fast_rcp(1.0f + ex2(t)); }

// Quad DPP: 0x00/0x55/0xAA/0xFF broadcast lane j; 0xB1=xor1, 0x4E=xor2, 0x1B=xor3.
template <int CTRL>
__device__ __forceinline__ float qmov(float v) {
    return __int_as_float(
        __builtin_amdgcn_mov_dpp(__float_as_int(v), CTRL, 0xf, 0xf, false));
}

// packed f32 fma -> v_pk_fma_f32
__device__ __forceinline__ v2f fma2(v2f a, v2f b, v2f c) { return a * b + c; }

template <int N>
__device__ __forceinline__ void waitv() {
    asm volatile("s_waitcnt vmcnt(%0)" :: "n"(N) : "memory");
}

typedef const __attribute__((address_space(1))) void gas_t;
typedef __attribute__((address_space(3))) void las_t;

__global__ __launch_bounds__(256, 2) void lstm_fused(
    const float* __restrict__ x,
    const float* __restrict__ w1,  const float* __restrict__ b1,
    const float* __restrict__ w2,  const float* __restrict__ b2,
    const float* __restrict__ wih, const float* __restrict__ whh,
    const float* __restrict__ bih, const float* __restrict__ bhh,
    const float* __restrict__ w3,  const float* __restrict__ b3,
    float* __restrict__ out)
{
    // 4 waves/block; per wave: 8 LDS buffers (1 KiB each), ~4-6 DMAs outstanding,
    // double-step pacing (one wait + one barrier per TWO steps). 32 KiB/block.
    __shared__ __align__(16) float lds[4][8][256];

    const int tid = threadIdx.x;
    const int w   = tid >> 6;          // wave in block
    const int l   = tid & 63;          // lane
    const int u   = l & 3;             // lane-in-quad (owns hidden unit u)
    const int e   = l >> 2;            // element (=row) within the wave's 16
    const int ebase = blockIdx.x * 64 + w * 16;
    const int elem  = ebase + e;

    // ---- DMA source pre-swizzle (dest linear: lane k -> bytes [16k,16k+16)) ----
    // slot q of row r holds part p=(q-perm(r))&3, perm(r)=(r+(r>>2))&3 (2-way max).
    // Parts: p0=bytes 0..15, p1=16..31, p2=32..47, p3=44..59 (word-11 dup, no OOB).
    const int perm_e = (e + (e >> 2)) & 3;
    const int p      = (u - perm_e) & 3;
    const int inrow  = (p < 3) ? p * 16 : 44;
    uint32_t off = (uint32_t)(ebase + e) * 60u + (uint32_t)inrow;   // slab-0 source byte

    auto gload = [&](int b, uint32_t o) {
        __builtin_amdgcn_global_load_lds(
            (gas_t*)((const char*)x + o),
            (las_t*)&lds[w][b][0], 16, 0, 0);
    };

    int sb[4];
#pragma unroll
    for (int pp = 0; pp < 4; ++pp) sb[pp] = (4 * e + ((pp + perm_e) & 3)) * 4;

    auto ldrow = [&](int b, v4f& F0, v4f& F1, v4f& F2, v4f& F3) {
        const float* B = &lds[w][b][0];
        F0 = *(const v4f*)(B + sb[0]);   // words 0..3
        F1 = *(const v4f*)(B + sb[1]);   // words 4..7
        F2 = *(const v4f*)(B + sb[2]);   // words 8..11
        F3 = *(const v4f*)(B + sb[3]);   // words 11..14 (x = dup of 11)
    };

    // ---- weights ----
    // fc1 (unit u): chains A=(0,1)(4,5)(8,9)(0*,12), B=(2,3)(6,7)(10,11)(13,14).
    v2f PA0, PA1, PA2, PA3, PB0, PB1, PB2, PB3, SEEDv;
    {
        const float* r = w1 + u * FEAT;
        PA0 = v2f{r[0],  r[1]};  PB0 = v2f{r[2],  r[3]};
        PA1 = v2f{r[4],  r[5]};  PB1 = v2f{r[6],  r[7]};
        PA2 = v2f{r[8],  r[9]};  PB2 = v2f{r[10], r[11]};
        PA3 = v2f{0.0f,  r[12]}; PB3 = v2f{r[13], r[14]};
        SEEDv = v2f{b1[u], 0.0f};
    }
    // fc2 (unit u), xor-permuted: a2n = sum_k w2[u][u^k] * h1[u^k], scaled -log2e
    const v2f W2X01 = v2f{-LOG2E * w2[u * 4 + u],       -LOG2E * w2[u * 4 + (u ^ 1)]};
    const v2f W2X23 = v2f{-LOG2E * w2[u * 4 + (u ^ 2)], -LOG2E * w2[u * 4 + (u ^ 3)]};
    const v2f B2seed = v2f{-LOG2E * b2[u], 0.0f};
    // gates (torch order i,f,g,o), xor-permuted over the source index.
    v2f WIx[4][2], WHx[4][2], BIg[4];
#pragma unroll
    for (int g = 0; g < 4; ++g) {
        const float sg = (g == 2) ? (2.0f * LOG2E) : -LOG2E;
        const int row = (g * 4 + u) * 4;
        WIx[g][0] = v2f{sg * wih[row + u],       sg * wih[row + (u ^ 1)]};
        WIx[g][1] = v2f{sg * wih[row + (u ^ 2)], sg * wih[row + (u ^ 3)]};
        WHx[g][0] = v2f{sg * whh[row + u],       sg * whh[row + (u ^ 1)]};
        WHx[g][1] = v2f{sg * whh[row + (u ^ 2)], sg * whh[row + (u ^ 3)]};
        BIg[g]    = v2f{sg * (bih[g * 4 + u] + bhh[g * 4 + u]), 0.0f};
    }
    const float W3v = -LOG2E * w3[u];
    const float B3v = -LOG2E * b3[0];

    float h = 0.0f;
    float cs = 0.0f;   // scaled cell state: cs = 2*log2e * c

    auto step = [&](v4f F0, v4f F1, v4f F2, v4f F3) {
        // fc1 (unit u): 8 pk_fma over aligned v2f slices
        v2f accA = fma2(PA0, F0.xy, fma2(PA1, F1.xy,
                   fma2(PA2, F2.xy, fma2(PA3, F3.xy, SEEDv))));
        v2f accB = fma2(PB0, F0.zw, fma2(PB1, F1.zw,
                   fma2(PB2, F2.zw, fma2(PB3, F3.zw, v2f{0.0f, 0.0f}))));
        const v2f accS = accA + accB;
        const float h1 = fmaxf(accS.x + accS.y, 0.0f);
        // fc2 + sigmoid via xor-DPP fetch (own + 3 neighbors)
        const v2f H01 = v2f{h1, qmov<0xB1>(h1)};
        const v2f H23 = v2f{qmov<0x4E>(h1), qmov<0x1B>(h1)};
        const v2f a2 = fma2(W2X01, H01, fma2(W2X23, H23, B2seed));
        const float h2 = sig2(a2.x + a2.y);
        // gate dots: xor-DPP pairs for h2 and h
        const v2f Q01 = v2f{h2, qmov<0xB1>(h2)};
        const v2f Q23 = v2f{qmov<0x4E>(h2), qmov<0x1B>(h2)};
        const v2f P01 = v2f{h, qmov<0xB1>(h)};
        const v2f P23 = v2f{qmov<0x4E>(h), qmov<0x1B>(h)};
        v2f A[4];
#pragma unroll
        for (int g = 0; g < 4; ++g)
            A[g] = fma2(WIx[g][0], Q01, fma2(WIx[g][1], Q23,
                   fma2(WHx[g][0], P01, fma2(WHx[g][1], P23, BIg[g]))));
        const float ig = sig2(A[0].x + A[0].y);
        const float fg = sig2(A[1].x + A[1].y);
        // gt pre-scaled by 2*log2e: gt2 = 2L - 4L*sig2(.)
        const float gt2 = fmaf(-4.0f * LOG2E, sig2(A[2].x + A[2].y), 2.0f * LOG2E);
        const float og = sig2(A[3].x + A[3].y);
        cs = fmaf(fg, cs, ig * gt2);               // cs = 2L*c
        const float tc = fmaf(-2.0f, sig2(cs), 1.0f);   // tanh(c)
        h = og * tc;
    };

    // ---- prologue: issue slabs 0..5; land 0,1; read rows 0,1 ----
#pragma unroll
    for (int b = 0; b < 6; ++b) { gload(b, off); off += SLABBYTES; }
    waitv<4>();
    v4f F0, F1, F2, F3, G0, G1, G2, G3;
    ldrow(0, F0, F1, F2, F3);
    ldrow(1, G0, G1, G2, G3);

    // ---- main: double-steps D=0..27 (7 phases x 4), then D=28 explicit ----
    // Iter D: wait slabs 2D+2,2D+3 landed (outstanding->2); read rows 2D+2,2D+3;
    // issue slabs 2D+6,2D+7 (buffers (2D-2)&7,(2D-1)&7, freed at iter D-1);
    // compute steps 2D,2D+1 from F,G; swap.
#pragma unroll 1
    for (int ph = 0; ph < 7; ++ph) {
#pragma unroll
        for (int d = 0; d < 4; ++d) {              // D = 4*ph + d
            waitv<2>();
            v4f N0, N1, N2, N3, M0, M1, M2, M3;
            ldrow((2 * d + 2) & 7, N0, N1, N2, N3);
            ldrow((2 * d + 3) & 7, M0, M1, M2, M3);
            gload((2 * d + 6) & 7, off);  off += SLABBYTES;
            gload((2 * d + 7) & 7, off);  off += SLABBYTES;
            __builtin_amdgcn_sched_barrier(0);
            step(F0, F1, F2, F3);                  // step 2D
            step(G0, G1, G2, G3);                  // step 2D+1
            F0 = N0; F1 = N1; F2 = N2; F3 = N3;
            G0 = M0; G1 = M1; G2 = M2; G3 = M3;
        }
    }
    {   // D=28: steps 56,57; read rows 58,59; issue slabs 62,63
        waitv<2>();
        v4f N0, N1, N2, N3, M0, M1, M2, M3;
        ldrow(2, N0, N1, N2, N3);
        ldrow(3, M0, M1, M2, M3);
        gload(6, off);  off += SLABBYTES;
        gload(7, off);  off += SLABBYTES;
        __builtin_amdgcn_sched_barrier(0);
        step(F0, F1, F2, F3);
        step(G0, G1, G2, G3);
        F0 = N0; F1 = N1; F2 = N2; F3 = N3;
        G0 = M0; G1 = M1; G2 = M2; G3 = M3;
    }
    {   // D=29: steps 58,59; read rows 60,61 (slabs 60,61 landed -> outstanding 2)
        waitv<2>();
        v4f N0, N1, N2, N3, M0, M1, M2, M3;
        ldrow(4, N0, N1, N2, N3);
        ldrow(5, M0, M1, M2, M3);
        __builtin_amdgcn_sched_barrier(0);
        step(F0, F1, F2, F3);
        step(G0, G1, G2, G3);
        F0 = N0; F1 = N1; F2 = N2; F3 = N3;
        G0 = M0; G1 = M1; G2 = M2; G3 = M3;
    }
    {   // D=30: steps 60,61; read rows 62,63 (all landed)
        waitv<0>();
        v4f N0, N1, N2, N3, M0, M1, M2, M3;
        ldrow(6, N0, N1, N2, N3);
        ldrow(7, M0, M1, M2, M3);
        __builtin_amdgcn_sched_barrier(0);
        step(F0, F1, F2, F3);
        step(G0, G1, G2, G3);
        F0 = N0; F1 = N1; F2 = N2; F3 = N3;
        G0 = M0; G1 = M1; G2 = M2; G3 = M3;
    }
    step(F0, F1, F2, F3);                          // step 62
    step(G0, G1, G2, G3);                          // step 63

    // ---- head: out[e] = sigmoid(w3·h + b3), quad reduction (scaled) ----
    float pr = W3v * h;
    pr += qmov<0xB1>(pr);
    pr += qmov<0x4E>(pr);
    if (u == 0) out[elem] = sig2(pr + B3v);
}

extern "C" void kernel_launch(void* const* d_in, const int* in_sizes, int n_in,
                              void* d_out, int out_size, void* d_ws, size_t ws_size,
                              hipStream_t stream) {
    (void)in_sizes; (void)n_in; (void)d_ws; (void)ws_size; (void)out_size;
    const float* x   = (const float*)d_in[0];
    const float* w1  = (const float*)d_in[1];
    const float* b1  = (const float*)d_in[2];
    const float* w2  = (const float*)d_in[3];
    const float* b2  = (const float*)d_in[4];
    const float* wih = (const float*)d_in[5];
    const float* whh = (const float*)d_in[6];
    const float* bih = (const float*)d_in[7];
    const float* bhh = (const float*)d_in[8];
    const float* w3  = (const float*)d_in[9];
    const float* b3  = (const float*)d_in[10];
    float* out = (float*)d_out;

    // 512 blocks x 256 threads = 2048 waves; one quad (4 lanes) per batch element.
    lstm_fused<<<dim3(512), dim3(256), 0, stream>>>(
        x, w1, b1, w2, b2, wih, whh, bih, bhh, w3, b3, out);
}